// Round 11
// baseline (265.069 us; speedup 1.0000x reference)
//
#include <hip/hip_runtime.h>

// ---------------------------------------------------------------------------
// TrendAttentionLayer, round 10.
// Algebra (R2-R9): only attn1 computed; attn2/attn3 = row subsets fanned out
// at store time; single weighted softmax/colsum (w = 1+[l%2==0]+[l%3==0]).
// R10 = R9 with ONE change in attn_fused: ALL global stores moved AFTER the
// last __syncthreads. Rationale: hipcc emits s_waitcnt vmcnt(0) before every
// s_barrier, so R9's stores-then-barrier order forced each block to fully
// drain ~235KB of score stores before softmax -> serialized write drain at
// 2 blocks/CU. Now: stats barriers happen with vmcnt==0 (cheap), acc stays
// RAW (exp computed on the fly, twice), and the score stores issue at the
// kernel tail with no trailing barrier -> wave retires, drain overlaps the
// next block's MFMA phase. Math bit-identical to R9.
// ---------------------------------------------------------------------------

typedef short s16x8 __attribute__((ext_vector_type(8)));
typedef float f32x4 __attribute__((ext_vector_type(4)));
typedef unsigned short u16;
typedef unsigned short u16x4 __attribute__((ext_vector_type(4)));

#define MFMA16(a, b, c) __builtin_amdgcn_mfma_f32_16x16x32_bf16((a), (b), (c), 0, 0, 0)

__device__ __forceinline__ u16 f32_to_bf16(float f) {
  unsigned u = __builtin_bit_cast(unsigned, f);
  unsigned r = u + 0x7fffu + ((u >> 16) & 1u);  // RTNE
  return (u16)(r >> 16);
}
__device__ __forceinline__ void split1(float x, u16& h, u16& l) {
  h = f32_to_bf16(x);
  l = f32_to_bf16(x - __builtin_bit_cast(float, (unsigned)h << 16));
}

// ---------------------------------------------------------------------------
// Kernel A: split ALL inputs into frag-major hi/lo planes in one launch.
// grid (1152, 3): y selects matrix (q/k/v); x<1024 -> X planes, x>=1024 -> W.
// Frag-major: element (row16 = mt*16+lr, k = kc*32+g*8+j) ->
//   [((mt*16+kc)*64 + g*16 + lr)*8 + j].
// ---------------------------------------------------------------------------
__global__ __launch_bounds__(256) void split_all(const float* __restrict__ in_q,
                                                 const float* __restrict__ in_k,
                                                 const float* __restrict__ in_v,
                                                 const float* __restrict__ Wq,
                                                 const float* __restrict__ Wk,
                                                 const float* __restrict__ Wv,
                                                 u16* __restrict__ Xsplit,
                                                 u16* __restrict__ Wsplit) {
  int which = blockIdx.y;  // 0,1,2
  int bx = blockIdx.x;
  if (bx < 1024) {
    const float* X = (which == 0) ? in_q : (which == 1) ? in_k : in_v;
    u16* Xh = Xsplit + (size_t)which * 2 * 2097152;
    u16* Xl = Xh + 2097152;
    int t = bx * 256 + threadIdx.x;  // < 262144
    int lane = t & 63;
    int kc = (t >> 6) & 15;
    int mt = t >> 10;
    int lr = lane & 15, g = lane >> 4;
    const float* p = X + (size_t)(mt * 16 + lr) * 512 + kc * 32 + g * 8;
    float4 a = *(const float4*)p;
    float4 b = *(const float4*)(p + 4);
    float x[8] = {a.x, a.y, a.z, a.w, b.x, b.y, b.z, b.w};
    s16x8 hv, lv;
#pragma unroll
    for (int j = 0; j < 8; ++j) {
      u16 hh, ll;
      split1(x[j], hh, ll);
      hv[j] = (short)hh;
      lv[j] = (short)ll;
    }
    size_t off = (size_t)t * 8;
    *(s16x8*)(Xh + off) = hv;
    *(s16x8*)(Xl + off) = lv;
  } else {
    const float* W = (which == 0) ? Wq : (which == 1) ? Wk : Wv;
    u16* Wh = Wsplit + (size_t)which * 2 * 262144;
    u16* Wl = Wh + 262144;
    int t = (bx - 1024) * 256 + threadIdx.x;  // < 32768
    int lane = t & 63;
    int kc = (t >> 6) & 15;
    int nt = t >> 10;
    int lr = lane & 15, g = lane >> 4;
    s16x8 hv, lv;
#pragma unroll
    for (int j = 0; j < 8; ++j) {
      float x = W[(size_t)(kc * 32 + g * 8 + j) * 512 + nt * 16 + lr];
      u16 hh, ll;
      split1(x, hh, ll);
      hv[j] = (short)hh;
      lv[j] = (short)ll;
    }
    size_t off = (size_t)t * 8;
    *(s16x8*)(Wh + off) = hv;
    *(s16x8*)(Wl + off) = lv;
  }
}

// ---------------------------------------------------------------------------
// Kernel 1: all three projection GEMMs, SWAPPED operands (A=W, B=X):
// D row = W-row (output col n), D col = lane&15 = X-row (output row m).
// -> per lane 4 consecutive n: float4 stores (v), u16x4 stores (q/k).
// 64x64 block tile, 4 waves 2x2, pure loads+MFMA K-loop. (validated R7-R9)
// ---------------------------------------------------------------------------
__global__ __launch_bounds__(256) void proj_gemm3(const u16* __restrict__ Xsplit,
                                                  const u16* __restrict__ Wsplit,
                                                  const float* __restrict__ bq,
                                                  const float* __restrict__ bk,
                                                  const float* __restrict__ bv,
                                                  float* __restrict__ vout,
                                                  u16* __restrict__ qh,
                                                  u16* __restrict__ ql,
                                                  u16* __restrict__ kh,
                                                  u16* __restrict__ kl) {
  int z = blockIdx.z;
  const u16* Xh = Xsplit + (size_t)z * 2 * 2097152;
  const u16* Xl = Xh + 2097152;
  const u16* Wh = Wsplit + (size_t)z * 2 * 262144;
  const u16* Wl = Wh + 262144;
  const float* bias = (z == 0) ? bq : (z == 1) ? bk : bv;
  u16* Yhi = (z == 0) ? qh : kh;
  u16* Ylo = (z == 0) ? ql : kl;

  int tid = threadIdx.x;
  int wid = tid >> 6, lane = tid & 63;
  int wr = wid >> 1, wc = wid & 1;
  int mtb = blockIdx.y * 4 + wr * 2;  // X 16-row tile base, 0..255
  int ntb = blockIdx.x * 4 + wc * 2;  // W 16-row tile base, 0..31

  f32x4 zero = {0.f, 0.f, 0.f, 0.f};
  f32x4 acc[2][2];
#pragma unroll
  for (int m = 0; m < 2; ++m)
#pragma unroll
    for (int n = 0; n < 2; ++n) acc[m][n] = zero;

  for (int kc = 0; kc < 16; ++kc) {
    s16x8 xh[2], xl[2], wh[2], wl[2];
#pragma unroll
    for (int m = 0; m < 2; ++m) {
      size_t off = ((size_t)((mtb + m) * 16 + kc) * 64 + lane) * 8;
      xh[m] = *(const s16x8*)(Xh + off);
      xl[m] = *(const s16x8*)(Xl + off);
    }
#pragma unroll
    for (int n = 0; n < 2; ++n) {
      size_t off = ((size_t)((ntb + n) * 16 + kc) * 64 + lane) * 8;
      wh[n] = *(const s16x8*)(Wh + off);
      wl[n] = *(const s16x8*)(Wl + off);
    }
#pragma unroll
    for (int m = 0; m < 2; ++m)
#pragma unroll
      for (int n = 0; n < 2; ++n) {
        acc[m][n] = MFMA16(wh[n], xh[m], acc[m][n]);
        acc[m][n] = MFMA16(wh[n], xl[m], acc[m][n]);
        acc[m][n] = MFMA16(wl[n], xh[m], acc[m][n]);
      }
  }
  // D layout (swapped): col = lane&15 -> m (X row); row = (lane>>4)*4+r -> n.
  int cn = lane & 15, rg = lane >> 4;
#pragma unroll
  for (int m = 0; m < 2; ++m) {
    int row = (mtb + m) * 16 + cn;  // output Y row (0..4095)
#pragma unroll
    for (int n = 0; n < 2; ++n) {
      int nc0 = (ntb + n) * 16 + rg * 4;  // output col base, 4 consecutive
      f32x4 b4 = *(const f32x4*)(bias + nc0);
      f32x4 y;
#pragma unroll
      for (int r = 0; r < 4; ++r) y[r] = acc[m][n][r] + b4[r];
      if (z == 2) {
        *(f32x4*)(vout + (size_t)row * 512 + nc0) = y;
      } else {
        int b = row >> 11, l = row & 2047;
        int h = nc0 >> 6;           // 4 cols stay within one head (4-aligned)
        int e0 = nc0 & 63;          // j stays within one octet (e0%8 in {0,4})
        int bh2 = b * 8 + h;
        int lt = l >> 4, lr2 = l & 15;
        int kc2 = e0 >> 5, g2 = (e0 >> 3) & 3, j0 = e0 & 7;
        size_t idx = ((((size_t)bh2 * 128 + lt) * 2 + kc2) * 64 + g2 * 16 + lr2) * 8 + j0;
        u16x4 hv, lv;
#pragma unroll
        for (int r = 0; r < 4; ++r) {
          u16 hh, ll;
          split1(y[r], hh, ll);
          hv[r] = hh;
          lv[r] = ll;
        }
        *(u16x4*)(Yhi + idx) = hv;
        *(u16x4*)(Ylo + idx) = lv;
      }
    }
  }
}

// ---------------------------------------------------------------------------
// Kernel 2: FUSED attn + softmax + colsum — R9 structure, STORES LAST.
// Block: 16 q-rows x 2048 s-cols, 512 threads = 8 waves x 256 cols,
// acc[16] f32x4 = 64 VGPR holding RAW scores until the end.
// Order: MFMA -> stats (3 cheap barriers, vmcnt already 0, exp on the fly)
// -> partials + raw-score stores at the tail, NO trailing barrier.
// ---------------------------------------------------------------------------
__global__ __launch_bounds__(512, 4) void attn_fused(const u16* __restrict__ qh,
                                                     const u16* __restrict__ ql,
                                                     const u16* __restrict__ kh,
                                                     const u16* __restrict__ kl,
                                                     float* __restrict__ a1,
                                                     float* __restrict__ a2,
                                                     float* __restrict__ a3,
                                                     float* __restrict__ partials) {
  int bh = blockIdx.y;    // 0..15
  int lblk = blockIdx.x;  // 0..127 (16 rows each)
  int tid = threadIdx.x, wid = tid >> 6, lane = tid & 63;

  // A-operand: the block's 16 q rows (same for every wave).
  s16x8 qhf[2], qlf[2];
#pragma unroll
  for (int kc = 0; kc < 2; ++kc) {
    size_t off = ((((size_t)bh * 128 + lblk) * 2 + kc) * 64 + lane) * 8;
    qhf[kc] = *(const s16x8*)(qh + off);
    qlf[kc] = *(const s16x8*)(ql + off);
  }

  f32x4 acc[16];
#pragma unroll
  for (int t = 0; t < 16; ++t) acc[t] = (f32x4){0.f, 0.f, 0.f, 0.f};

#pragma unroll
  for (int t = 0; t < 16; ++t) {
    int st = wid * 16 + t;  // k 16-row tile, 0..127
#pragma unroll
    for (int kc = 0; kc < 2; ++kc) {
      size_t off = ((((size_t)bh * 128 + st) * 2 + kc) * 64 + lane) * 8;
      s16x8 khf = *(const s16x8*)(kh + off);
      s16x8 klf = *(const s16x8*)(kl + off);
      acc[t] = MFMA16(qhf[kc], khf, acc[t]);
      acc[t] = MFMA16(qhf[kc], klf, acc[t]);
      acc[t] = MFMA16(qlf[kc], khf, acc[t]);
    }
  }

  // D layout: col = lane&15 = cn -> s offset; row = (lane>>4)*4+r -> q-row.
  int cn = lane & 15, rg = lane >> 4;
  int lbase = lblk * 16;

  // ---- row max (wave's 256 cols -> across 8 waves via LDS) ----------------
  // No stores outstanding -> the barriers' implicit vmcnt(0) is already met.
  __shared__ float lred[16][8];
  float mrow[4];
#pragma unroll
  for (int r = 0; r < 4; ++r) {
    float m = acc[0][r];
#pragma unroll
    for (int t = 1; t < 16; ++t) m = fmaxf(m, acc[t][r]);
#pragma unroll
    for (int o = 1; o < 16; o <<= 1) m = fmaxf(m, __shfl_xor(m, o));
    mrow[r] = m;
  }
  if (cn == 0) {
#pragma unroll
    for (int r = 0; r < 4; ++r) lred[rg * 4 + r][wid] = mrow[r];
  }
  __syncthreads();
  float mfin[4];
#pragma unroll
  for (int r = 0; r < 4; ++r) {
    int rr = rg * 4 + r;
    float m = lred[rr][0];
#pragma unroll
    for (int w = 1; w < 8; ++w) m = fmaxf(m, lred[rr][w]);
    mfin[r] = m;
  }
  __syncthreads();  // lred reused for sums

  // ---- row sums: exp on the fly (acc stays RAW) ---------------------------
  float zrow[4] = {0.f, 0.f, 0.f, 0.f};
#pragma unroll
  for (int t = 0; t < 16; ++t) {
#pragma unroll
    for (int r = 0; r < 4; ++r) zrow[r] += __expf(acc[t][r] - mfin[r]);
  }
#pragma unroll
  for (int r = 0; r < 4; ++r) {
#pragma unroll
    for (int o = 1; o < 16; o <<= 1) zrow[r] += __shfl_xor(zrow[r], o);
  }
  if (cn == 0) {
#pragma unroll
    for (int r = 0; r < 4; ++r) lred[rg * 4 + r][wid] = zrow[r];
  }
  __syncthreads();
  float winv[4];
#pragma unroll
  for (int r = 0; r < 4; ++r) {
    int rr = rg * 4 + r;
    int l = lbase + rr;
    float zs = lred[rr][0];
#pragma unroll
    for (int w = 1; w < 8; ++w) zs += lred[rr][w];
    float w_ = 1.f + (((l & 1) == 0) ? 1.f : 0.f) + ((l % 3 == 0) ? 1.f : 0.f);
    winv[r] = w_ / zs;
  }

  // ---- weighted colsum (second on-the-fly exp) ----------------------------
  __shared__ float pcol[2048];
#pragma unroll
  for (int t = 0; t < 16; ++t) {
    float cs = __expf(acc[t][0] - mfin[0]) * winv[0] +
               __expf(acc[t][1] - mfin[1]) * winv[1] +
               __expf(acc[t][2] - mfin[2]) * winv[2] +
               __expf(acc[t][3] - mfin[3]) * winv[3];
    cs += __shfl_xor(cs, 16);
    cs += __shfl_xor(cs, 32);
    if (lane < 16) pcol[wid * 256 + t * 16 + cn] = cs;
  }
  __syncthreads();  // LDS-only dependency; vmcnt still 0

  // ---- TAIL: all global stores, no trailing barrier -----------------------
  size_t pb = ((size_t)bh * 128 + lblk) * 2048;
  *(f32x4*)&partials[pb + tid * 4] = *(const f32x4*)&pcol[tid * 4];

  float* A1 = a1 + (size_t)bh * 2048 * 2048;
  float* A2 = a2 + (size_t)bh * 1024 * 2048;
  float* A3 = a3 + (size_t)bh * 683 * 2048;
#pragma unroll
  for (int r = 0; r < 4; ++r) {
    int l = lbase + rg * 4 + r;
    float* p1 = A1 + (size_t)l * 2048 + wid * 256 + cn;
#pragma unroll
    for (int t = 0; t < 16; ++t) p1[t * 16] = acc[t][r];
    if ((l & 1) == 0) {
      float* p2 = A2 + (size_t)(l >> 1) * 2048 + wid * 256 + cn;
#pragma unroll
      for (int t = 0; t < 16; ++t) p2[t * 16] = acc[t][r];
    }
    if (l % 3 == 0) {
      float* p3 = A3 + (size_t)(l / 3) * 2048 + wid * 256 + cn;
#pragma unroll
      for (int t = 0; t < 16; ++t) p3[t * 16] = acc[t][r];
    }
  }
}

// ---------------------------------------------------------------------------
// Kernel 3: csum_total[bh,s] = sum over 128 row-block partials.
// ---------------------------------------------------------------------------
__global__ __launch_bounds__(256) void reduce_partials(const float* __restrict__ partials,
                                                       float* __restrict__ csum) {
  int s = blockIdx.x * 256 + threadIdx.x;
  int bh = blockIdx.y;
  float acc = 0.f;
  for (int j = 0; j < 128; ++j) acc += partials[((size_t)(bh * 128 + j)) * 2048 + s];
  csum[(size_t)bh * 2048 + s] = acc;
}

// ---------------------------------------------------------------------------
// Kernel 4: out[b,s,h*64+e] = v[b,s,h,e] * csum_total[b,h,s] / 3
// ---------------------------------------------------------------------------
__global__ __launch_bounds__(256) void final_out(const float* __restrict__ v,
                                                 const float* __restrict__ csum,
                                                 float* __restrict__ out) {
  int idx = blockIdx.x * 256 + threadIdx.x;  // float4 index
  int h = (idx >> 4) & 7;
  int s = (idx >> 7) & 2047;
  int b = idx >> 18;
  float4 vv = ((const float4*)v)[idx];
  float c = csum[(size_t)(b * 8 + h) * 2048 + s] * (1.f / 3.f);
  float4 o = {vv.x * c, vv.y * c, vv.z * c, vv.w * c};
  ((float4*)out)[idx] = o;
}

// ---------------------------------------------------------------------------
extern "C" void kernel_launch(void* const* d_in, const int* in_sizes, int n_in,
                              void* d_out, int out_size, void* d_ws, size_t ws_size,
                              hipStream_t stream) {
  const float* queries = (const float*)d_in[0];
  const float* keys    = (const float*)d_in[1];
  const float* values  = (const float*)d_in[2];
  const float* Wq = (const float*)d_in[3];
  const float* bq = (const float*)d_in[4];
  const float* Wk = (const float*)d_in[5];
  const float* bk = (const float*)d_in[6];
  const float* Wv = (const float*)d_in[7];
  const float* bv = (const float*)d_in[8];

  float* out = (float*)d_out;   // (2,2048,512)    = 2097152
  float* a1 = out + 2097152;    // (2,8,2048,2048) = 67108864
  float* a2 = a1 + 67108864;    // (2,8,1024,2048) = 33554432
  float* a3 = a2 + 33554432;    // (2,8, 683,2048) = 22380544

  float* ws = (float*)d_ws;
  float* v = ws;                        // 8 MB
  u16* qh = (u16*)(v + 2097152);        // 4 MB each
  u16* ql = qh + 2097152;
  u16* kh = ql + 2097152;
  u16* kl = kh + 2097152;
  u16* Wsplit = kl + 2097152;           // 6 x 262144 u16 = 3 MB
  u16* Xsplit = Wsplit + 6 * 262144;    // 6 x 2097152 u16 = 24 MB
  // aliases (dead after proj_gemm3):
  float* partials = (float*)Xsplit;     // 16*128*2048 f32 = 16 MB (<= 24 MB)
  float* csum = (float*)Wsplit;         // 32768 f32 (<= 3 MB)

  split_all<<<dim3(1152, 3), 256, 0, stream>>>(queries, keys, values, Wq, Wk, Wv,
                                               Xsplit, Wsplit);

  proj_gemm3<<<dim3(8, 64, 3), 256, 0, stream>>>(Xsplit, Wsplit, bq, bk, bv, v,
                                                 qh, ql, kh, kl);

  attn_fused<<<dim3(128, 16), 512, 0, stream>>>(qh, ql, kh, kl, a1, a2, a3, partials);

  reduce_partials<<<dim3(8, 16), 256, 0, stream>>>(partials, csum);

  final_out<<<dim3(2048), 256, 0, stream>>>(v, csum, out);
}

// Round 12
// 193.446 us; speedup vs baseline: 1.3703x; 1.3703x over previous
//
#include <hip/hip_runtime.h>

// ---------------------------------------------------------------------------
// TrendAttentionLayer, round 11.
// Algebra (R2-R10): only attn1 computed; attn2/attn3 = row subsets fanned out
// at store time; single weighted softmax/colsum (w = 1+[l%2==0]+[l%3==0]).
// R11 = R9 (best: 198us; stores-early order restored after R10's tail-store
// regression) + TWO L2-locality changes in attn_fused:
//  1. XCD-aware block swizzle: all 128 blocks of a bh land on ONE XCD
//     (xcd = wg&7 dispatch round-robin; bh = xcd*2 + bit) -> per-XCD k-panel
//     working set = 2 panels = 1MB << 4MB L2. Kills the ~470MB k re-fetch
//     (attn traffic was ~1.0GB vs 0.53GB compulsory).
//  2. Score stores NT: the 0.5GB write stream bypasses L2 instead of
//     evicting the resident k panels (NT ~ cached when thrashing, R6 vs R9).
// ---------------------------------------------------------------------------

typedef short s16x8 __attribute__((ext_vector_type(8)));
typedef float f32x4 __attribute__((ext_vector_type(4)));
typedef unsigned short u16;
typedef unsigned short u16x4 __attribute__((ext_vector_type(4)));

#define MFMA16(a, b, c) __builtin_amdgcn_mfma_f32_16x16x32_bf16((a), (b), (c), 0, 0, 0)

__device__ __forceinline__ u16 f32_to_bf16(float f) {
  unsigned u = __builtin_bit_cast(unsigned, f);
  unsigned r = u + 0x7fffu + ((u >> 16) & 1u);  // RTNE
  return (u16)(r >> 16);
}
__device__ __forceinline__ void split1(float x, u16& h, u16& l) {
  h = f32_to_bf16(x);
  l = f32_to_bf16(x - __builtin_bit_cast(float, (unsigned)h << 16));
}

// ---------------------------------------------------------------------------
// Kernel A: split ALL inputs into frag-major hi/lo planes in one launch.
// grid (1152, 3): y selects matrix (q/k/v); x<1024 -> X planes, x>=1024 -> W.
// Frag-major: element (row16 = mt*16+lr, k = kc*32+g*8+j) ->
//   [((mt*16+kc)*64 + g*16 + lr)*8 + j].
// ---------------------------------------------------------------------------
__global__ __launch_bounds__(256) void split_all(const float* __restrict__ in_q,
                                                 const float* __restrict__ in_k,
                                                 const float* __restrict__ in_v,
                                                 const float* __restrict__ Wq,
                                                 const float* __restrict__ Wk,
                                                 const float* __restrict__ Wv,
                                                 u16* __restrict__ Xsplit,
                                                 u16* __restrict__ Wsplit) {
  int which = blockIdx.y;  // 0,1,2
  int bx = blockIdx.x;
  if (bx < 1024) {
    const float* X = (which == 0) ? in_q : (which == 1) ? in_k : in_v;
    u16* Xh = Xsplit + (size_t)which * 2 * 2097152;
    u16* Xl = Xh + 2097152;
    int t = bx * 256 + threadIdx.x;  // < 262144
    int lane = t & 63;
    int kc = (t >> 6) & 15;
    int mt = t >> 10;
    int lr = lane & 15, g = lane >> 4;
    const float* p = X + (size_t)(mt * 16 + lr) * 512 + kc * 32 + g * 8;
    float4 a = *(const float4*)p;
    float4 b = *(const float4*)(p + 4);
    float x[8] = {a.x, a.y, a.z, a.w, b.x, b.y, b.z, b.w};
    s16x8 hv, lv;
#pragma unroll
    for (int j = 0; j < 8; ++j) {
      u16 hh, ll;
      split1(x[j], hh, ll);
      hv[j] = (short)hh;
      lv[j] = (short)ll;
    }
    size_t off = (size_t)t * 8;
    *(s16x8*)(Xh + off) = hv;
    *(s16x8*)(Xl + off) = lv;
  } else {
    const float* W = (which == 0) ? Wq : (which == 1) ? Wk : Wv;
    u16* Wh = Wsplit + (size_t)which * 2 * 262144;
    u16* Wl = Wh + 262144;
    int t = (bx - 1024) * 256 + threadIdx.x;  // < 32768
    int lane = t & 63;
    int kc = (t >> 6) & 15;
    int nt = t >> 10;
    int lr = lane & 15, g = lane >> 4;
    s16x8 hv, lv;
#pragma unroll
    for (int j = 0; j < 8; ++j) {
      float x = W[(size_t)(kc * 32 + g * 8 + j) * 512 + nt * 16 + lr];
      u16 hh, ll;
      split1(x, hh, ll);
      hv[j] = (short)hh;
      lv[j] = (short)ll;
    }
    size_t off = (size_t)t * 8;
    *(s16x8*)(Wh + off) = hv;
    *(s16x8*)(Wl + off) = lv;
  }
}

// ---------------------------------------------------------------------------
// Kernel 1: all three projection GEMMs, SWAPPED operands (A=W, B=X):
// D row = W-row (output col n), D col = lane&15 = X-row (output row m).
// -> per lane 4 consecutive n: float4 stores (v), u16x4 stores (q/k).
// 64x64 block tile, 4 waves 2x2, pure loads+MFMA K-loop. (validated R7-R10)
// ---------------------------------------------------------------------------
__global__ __launch_bounds__(256) void proj_gemm3(const u16* __restrict__ Xsplit,
                                                  const u16* __restrict__ Wsplit,
                                                  const float* __restrict__ bq,
                                                  const float* __restrict__ bk,
                                                  const float* __restrict__ bv,
                                                  float* __restrict__ vout,
                                                  u16* __restrict__ qh,
                                                  u16* __restrict__ ql,
                                                  u16* __restrict__ kh,
                                                  u16* __restrict__ kl) {
  int z = blockIdx.z;
  const u16* Xh = Xsplit + (size_t)z * 2 * 2097152;
  const u16* Xl = Xh + 2097152;
  const u16* Wh = Wsplit + (size_t)z * 2 * 262144;
  const u16* Wl = Wh + 262144;
  const float* bias = (z == 0) ? bq : (z == 1) ? bk : bv;
  u16* Yhi = (z == 0) ? qh : kh;
  u16* Ylo = (z == 0) ? ql : kl;

  int tid = threadIdx.x;
  int wid = tid >> 6, lane = tid & 63;
  int wr = wid >> 1, wc = wid & 1;
  int mtb = blockIdx.y * 4 + wr * 2;  // X 16-row tile base, 0..255
  int ntb = blockIdx.x * 4 + wc * 2;  // W 16-row tile base, 0..31

  f32x4 zero = {0.f, 0.f, 0.f, 0.f};
  f32x4 acc[2][2];
#pragma unroll
  for (int m = 0; m < 2; ++m)
#pragma unroll
    for (int n = 0; n < 2; ++n) acc[m][n] = zero;

  for (int kc = 0; kc < 16; ++kc) {
    s16x8 xh[2], xl[2], wh[2], wl[2];
#pragma unroll
    for (int m = 0; m < 2; ++m) {
      size_t off = ((size_t)((mtb + m) * 16 + kc) * 64 + lane) * 8;
      xh[m] = *(const s16x8*)(Xh + off);
      xl[m] = *(const s16x8*)(Xl + off);
    }
#pragma unroll
    for (int n = 0; n < 2; ++n) {
      size_t off = ((size_t)((ntb + n) * 16 + kc) * 64 + lane) * 8;
      wh[n] = *(const s16x8*)(Wh + off);
      wl[n] = *(const s16x8*)(Wl + off);
    }
#pragma unroll
    for (int m = 0; m < 2; ++m)
#pragma unroll
      for (int n = 0; n < 2; ++n) {
        acc[m][n] = MFMA16(wh[n], xh[m], acc[m][n]);
        acc[m][n] = MFMA16(wh[n], xl[m], acc[m][n]);
        acc[m][n] = MFMA16(wl[n], xh[m], acc[m][n]);
      }
  }
  // D layout (swapped): col = lane&15 -> m (X row); row = (lane>>4)*4+r -> n.
  int cn = lane & 15, rg = lane >> 4;
#pragma unroll
  for (int m = 0; m < 2; ++m) {
    int row = (mtb + m) * 16 + cn;  // output Y row (0..4095)
#pragma unroll
    for (int n = 0; n < 2; ++n) {
      int nc0 = (ntb + n) * 16 + rg * 4;  // output col base, 4 consecutive
      f32x4 b4 = *(const f32x4*)(bias + nc0);
      f32x4 y;
#pragma unroll
      for (int r = 0; r < 4; ++r) y[r] = acc[m][n][r] + b4[r];
      if (z == 2) {
        *(f32x4*)(vout + (size_t)row * 512 + nc0) = y;
      } else {
        int b = row >> 11, l = row & 2047;
        int h = nc0 >> 6;           // 4 cols stay within one head (4-aligned)
        int e0 = nc0 & 63;          // j stays within one octet (e0%8 in {0,4})
        int bh2 = b * 8 + h;
        int lt = l >> 4, lr2 = l & 15;
        int kc2 = e0 >> 5, g2 = (e0 >> 3) & 3, j0 = e0 & 7;
        size_t idx = ((((size_t)bh2 * 128 + lt) * 2 + kc2) * 64 + g2 * 16 + lr2) * 8 + j0;
        u16x4 hv, lv;
#pragma unroll
        for (int r = 0; r < 4; ++r) {
          u16 hh, ll;
          split1(y[r], hh, ll);
          hv[r] = hh;
          lv[r] = ll;
        }
        *(u16x4*)(Yhi + idx) = hv;
        *(u16x4*)(Ylo + idx) = lv;
      }
    }
  }
}

// ---------------------------------------------------------------------------
// Kernel 2: FUSED attn + softmax + colsum — R9 structure + XCD swizzle + NT.
// 1-D grid 2048: xcd = wg&7 (dispatch round-robin), bh = xcd*2 + bit ->
// each bh's 128 blocks run on one XCD; its 1MB k panel stays L2-resident.
// Block: 16 q-rows x 2048 s-cols, 512 threads = 8 waves x 256 cols,
// acc[16] f32x4. Stores (NT) right after MFMA (R9 order), then softmax.
// ---------------------------------------------------------------------------
__global__ __launch_bounds__(512, 4) void attn_fused(const u16* __restrict__ qh,
                                                     const u16* __restrict__ ql,
                                                     const u16* __restrict__ kh,
                                                     const u16* __restrict__ kl,
                                                     float* __restrict__ a1,
                                                     float* __restrict__ a2,
                                                     float* __restrict__ a3,
                                                     float* __restrict__ partials) {
  int wg = blockIdx.x;            // 0..2047
  int xcd = wg & 7;               // dispatch: wgid % 8 -> XCD
  int idx = wg >> 3;              // 0..255
  int bh = xcd * 2 + (idx >> 7);  // 0..15: 2 bh per XCD
  int lblk = idx & 127;           // 0..127
  int tid = threadIdx.x, wid = tid >> 6, lane = tid & 63;

  // A-operand: the block's 16 q rows (same for every wave).
  s16x8 qhf[2], qlf[2];
#pragma unroll
  for (int kc = 0; kc < 2; ++kc) {
    size_t off = ((((size_t)bh * 128 + lblk) * 2 + kc) * 64 + lane) * 8;
    qhf[kc] = *(const s16x8*)(qh + off);
    qlf[kc] = *(const s16x8*)(ql + off);
  }

  f32x4 acc[16];
#pragma unroll
  for (int t = 0; t < 16; ++t) acc[t] = (f32x4){0.f, 0.f, 0.f, 0.f};

#pragma unroll
  for (int t = 0; t < 16; ++t) {
    int st = wid * 16 + t;  // k 16-row tile, 0..127
#pragma unroll
    for (int kc = 0; kc < 2; ++kc) {
      size_t off = ((((size_t)bh * 128 + st) * 2 + kc) * 64 + lane) * 8;
      s16x8 khf = *(const s16x8*)(kh + off);
      s16x8 klf = *(const s16x8*)(kl + off);
      acc[t] = MFMA16(qhf[kc], khf, acc[t]);
      acc[t] = MFMA16(qhf[kc], klf, acc[t]);
      acc[t] = MFMA16(qlf[kc], khf, acc[t]);
    }
  }

  // ---- NT stores of raw scores (R9 order: before softmax) -----------------
  // D layout: col = lane&15 = cn -> s offset; row = (lane>>4)*4+r -> q-row.
  int cn = lane & 15, rg = lane >> 4;
  int lbase = lblk * 16;
  float* A1 = a1 + (size_t)bh * 2048 * 2048;
  float* A2 = a2 + (size_t)bh * 1024 * 2048;
  float* A3 = a3 + (size_t)bh * 683 * 2048;
#pragma unroll
  for (int r = 0; r < 4; ++r) {
    int l = lbase + rg * 4 + r;
    float* p1 = A1 + (size_t)l * 2048 + wid * 256 + cn;
#pragma unroll
    for (int t = 0; t < 16; ++t) __builtin_nontemporal_store(acc[t][r], p1 + t * 16);
    if ((l & 1) == 0) {
      float* p2 = A2 + (size_t)(l >> 1) * 2048 + wid * 256 + cn;
#pragma unroll
      for (int t = 0; t < 16; ++t) __builtin_nontemporal_store(acc[t][r], p2 + t * 16);
    }
    if (l % 3 == 0) {
      float* p3 = A3 + (size_t)(l / 3) * 2048 + wid * 256 + cn;
#pragma unroll
      for (int t = 0; t < 16; ++t) __builtin_nontemporal_store(acc[t][r], p3 + t * 16);
    }
  }

  // ---- row max (wave's 256 cols -> across 8 waves via LDS) ----------------
  __shared__ float lred[16][8];
  float mrow[4];
#pragma unroll
  for (int r = 0; r < 4; ++r) {
    float m = acc[0][r];
#pragma unroll
    for (int t = 1; t < 16; ++t) m = fmaxf(m, acc[t][r]);
#pragma unroll
    for (int o = 1; o < 16; o <<= 1) m = fmaxf(m, __shfl_xor(m, o));
    mrow[r] = m;
  }
  if (cn == 0) {
#pragma unroll
    for (int r = 0; r < 4; ++r) lred[rg * 4 + r][wid] = mrow[r];
  }
  __syncthreads();
  float mfin[4];
#pragma unroll
  for (int r = 0; r < 4; ++r) {
    int rr = rg * 4 + r;
    float m = lred[rr][0];
#pragma unroll
    for (int w = 1; w < 8; ++w) m = fmaxf(m, lred[rr][w]);
    mfin[r] = m;
  }
  __syncthreads();  // lred reused for sums

  // ---- exp in place + row sums --------------------------------------------
  float zrow[4] = {0.f, 0.f, 0.f, 0.f};
#pragma unroll
  for (int t = 0; t < 16; ++t) {
#pragma unroll
    for (int r = 0; r < 4; ++r) {
      float p = __expf(acc[t][r] - mfin[r]);
      acc[t][r] = p;
      zrow[r] += p;
    }
  }
#pragma unroll
  for (int r = 0; r < 4; ++r) {
#pragma unroll
    for (int o = 1; o < 16; o <<= 1) zrow[r] += __shfl_xor(zrow[r], o);
  }
  if (cn == 0) {
#pragma unroll
    for (int r = 0; r < 4; ++r) lred[rg * 4 + r][wid] = zrow[r];
  }
  __syncthreads();
  float winv[4];
#pragma unroll
  for (int r = 0; r < 4; ++r) {
    int rr = rg * 4 + r;
    int l = lbase + rr;
    float zs = lred[rr][0];
#pragma unroll
    for (int w = 1; w < 8; ++w) zs += lred[rr][w];
    float w_ = 1.f + (((l & 1) == 0) ? 1.f : 0.f) + ((l % 3 == 0) ? 1.f : 0.f);
    winv[r] = w_ / zs;
  }

  // ---- weighted colsum: 4 in-register + shfl over rg ----------------------
  __shared__ float pcol[2048];
#pragma unroll
  for (int t = 0; t < 16; ++t) {
    float cs = acc[t][0] * winv[0] + acc[t][1] * winv[1] + acc[t][2] * winv[2] +
               acc[t][3] * winv[3];
    cs += __shfl_xor(cs, 16);
    cs += __shfl_xor(cs, 32);
    if (lane < 16) pcol[wid * 256 + t * 16 + cn] = cs;
  }
  __syncthreads();
  size_t pb = ((size_t)bh * 128 + lblk) * 2048;
  *(f32x4*)&partials[pb + tid * 4] = *(const f32x4*)&pcol[tid * 4];
}

// ---------------------------------------------------------------------------
// Kernel 3: csum_total[bh,s] = sum over 128 row-block partials.
// ---------------------------------------------------------------------------
__global__ __launch_bounds__(256) void reduce_partials(const float* __restrict__ partials,
                                                       float* __restrict__ csum) {
  int s = blockIdx.x * 256 + threadIdx.x;
  int bh = blockIdx.y;
  float acc = 0.f;
  for (int j = 0; j < 128; ++j) acc += partials[((size_t)(bh * 128 + j)) * 2048 + s];
  csum[(size_t)bh * 2048 + s] = acc;
}

// ---------------------------------------------------------------------------
// Kernel 4: out[b,s,h*64+e] = v[b,s,h,e] * csum_total[b,h,s] / 3
// ---------------------------------------------------------------------------
__global__ __launch_bounds__(256) void final_out(const float* __restrict__ v,
                                                 const float* __restrict__ csum,
                                                 float* __restrict__ out) {
  int idx = blockIdx.x * 256 + threadIdx.x;  // float4 index
  int h = (idx >> 4) & 7;
  int s = (idx >> 7) & 2047;
  int b = idx >> 18;
  float4 vv = ((const float4*)v)[idx];
  float c = csum[(size_t)(b * 8 + h) * 2048 + s] * (1.f / 3.f);
  float4 o = {vv.x * c, vv.y * c, vv.z * c, vv.w * c};
  ((float4*)out)[idx] = o;
}

// ---------------------------------------------------------------------------
extern "C" void kernel_launch(void* const* d_in, const int* in_sizes, int n_in,
                              void* d_out, int out_size, void* d_ws, size_t ws_size,
                              hipStream_t stream) {
  const float* queries = (const float*)d_in[0];
  const float* keys    = (const float*)d_in[1];
  const float* values  = (const float*)d_in[2];
  const float* Wq = (const float*)d_in[3];
  const float* bq = (const float*)d_in[4];
  const float* Wk = (const float*)d_in[5];
  const float* bk = (const float*)d_in[6];
  const float* Wv = (const float*)d_in[7];
  const float* bv = (const float*)d_in[8];

  float* out = (float*)d_out;   // (2,2048,512)    = 2097152
  float* a1 = out + 2097152;    // (2,8,2048,2048) = 67108864
  float* a2 = a1 + 67108864;    // (2,8,1024,2048) = 33554432
  float* a3 = a2 + 33554432;    // (2,8, 683,2048) = 22380544

  float* ws = (float*)d_ws;
  float* v = ws;                        // 8 MB
  u16* qh = (u16*)(v + 2097152);        // 4 MB each
  u16* ql = qh + 2097152;
  u16* kh = ql + 2097152;
  u16* kl = kh + 2097152;
  u16* Wsplit = kl + 2097152;           // 6 x 262144 u16 = 3 MB
  u16* Xsplit = Wsplit + 6 * 262144;    // 6 x 2097152 u16 = 24 MB
  // aliases (dead after proj_gemm3):
  float* partials = (float*)Xsplit;     // 16*128*2048 f32 = 16 MB (<= 24 MB)
  float* csum = (float*)Wsplit;         // 32768 f32 (<= 3 MB)

  split_all<<<dim3(1152, 3), 256, 0, stream>>>(queries, keys, values, Wq, Wk, Wv,
                                               Xsplit, Wsplit);

  proj_gemm3<<<dim3(8, 64, 3), 256, 0, stream>>>(Xsplit, Wsplit, bq, bk, bv, v,
                                                 qh, ql, kh, kl);

  attn_fused<<<dim3(2048), 512, 0, stream>>>(qh, ql, kh, kl, a1, a2, a3, partials);

  reduce_partials<<<dim3(8, 16), 256, 0, stream>>>(partials, csum);

  final_out<<<dim3(2048), 256, 0, stream>>>(v, csum, out);
}